// Round 13
// baseline (358.884 us; speedup 1.0000x reference)
//
#include <hip/hip_runtime.h>
#include <stdint.h>

#define BATCH 4096
#define NEXP 64

typedef __bf16 bf16x8 __attribute__((ext_vector_type(8)));
typedef _Float16 f16x8 __attribute__((ext_vector_type(8)));
typedef float f32x4 __attribute__((ext_vector_type(4)));
typedef float f32x8 __attribute__((ext_vector_type(8)));
typedef unsigned int u32x4 __attribute__((ext_vector_type(4)));
typedef unsigned short u16x4 __attribute__((ext_vector_type(4)));
typedef unsigned short u16x8 __attribute__((ext_vector_type(8)));

__device__ __forceinline__ unsigned short f2bf(float f) {
  unsigned u = __builtin_bit_cast(unsigned, f);
  u += 0x7fffu + ((u >> 16) & 1u);
  return (unsigned short)(u >> 16);
}
__device__ __forceinline__ float bf2f(unsigned short h) {
  unsigned u = ((unsigned)h) << 16;
  return __builtin_bit_cast(float, u);
}
__device__ __forceinline__ unsigned short f2h(float f) {
  return __builtin_bit_cast(unsigned short, (_Float16)f);
}

// async global->LDS, 16B per lane.
__device__ __forceinline__ void async_copy16(const void* g, void* l) {
  __builtin_amdgcn_global_load_lds(
      (const __attribute__((address_space(1))) void*)(uintptr_t)g,
      (__attribute__((address_space(3))) void*)(uintptr_t)l, 16, 0, 0);
}

enum { AM_PLAIN = 0, AM_BN = 1 };

// ---------------------------------------------------------------------------
// MNet GEMM (bf16, unchanged).
// ---------------------------------------------------------------------------
template <int BM_, int BN_, int WR, int WC, int AMODE>
__global__ __launch_bounds__(256, 4) void gemm_k(
    const float* __restrict__ Af32, const float* __restrict__ scv,
    const float* __restrict__ shv, const float* __restrict__ alphaPtr,
    const unsigned short* __restrict__ PB, int K, int nsubsTot,
    float* __restrict__ Cp, const float* __restrict__ biasv, int N,
    int ktilesTot) {
  constexpr int MS = BM_ / 16;
  constexpr int NS = BN_ / 16;
  constexpr int WTM = BM_ / WR, WTN = BN_ / WC;
  constexpr int TM = WTM / 16, TN = WTN / 16;
  constexpr int PCH = MS / 2;

  __shared__ __align__(16) unsigned short As[2 * MS * 512];
  __shared__ __align__(16) unsigned short Bs[2 * NS * 512];

  const int tid = threadIdx.x;
  const int lane = tid & 63;
  const int wid = tid >> 6;
  const int wrow = wid / WC, wcol = wid % WC;

  const int m0 = blockIdx.x * BM_;
  const int ntile = blockIdx.y;
  const int n0 = ntile * BN_;

  float alpha = 0.f;
  if constexpr (AMODE == AM_BN) alpha = alphaPtr[0];

  f32x4 acc[TM][TN] = {};

  for (int kt = 0; kt < ktilesTot; ++kt) {
    const int k0 = kt * 64;

    for (int f = wid; f < 2 * NS; f += 4) {
      const int fkt = f / NS, fns = f % NS;
      const long fragIdx = (long)(k0 / 32 + fkt) * nsubsTot + (ntile * NS + fns);
      async_copy16(PB + fragIdx * 512 + lane * 8, &Bs[f * 512 + lane * 8]);
    }

#pragma unroll
    for (int p = 0; p < PCH; ++p) {
      const int id = p * 256 + tid;
      const int fA = id >> 6;
      const int q = id & 63;
      const int ksh = fA / MS, msub = fA % MS;
      const int kq = q >> 4, mrow = q & 15;
      const int m = msub * 16 + mrow;
      const int kg = k0 + ksh * 32 + kq * 8;
      const long mg = m0 + m;
      f32x8 vf;
      if constexpr (AMODE == AM_PLAIN) {
        const f32x4* src = (const f32x4*)(Af32 + mg * K + kg);
        f32x4 a0 = src[0], a1 = src[1];
#pragma unroll
        for (int j = 0; j < 4; ++j) { vf[j] = a0[j]; vf[4 + j] = a1[j]; }
      } else {
        const f32x4* src = (const f32x4*)(Af32 + mg * K + kg);
        f32x4 a0 = src[0], a1 = src[1];
        f32x4 s0 = *(const f32x4*)(scv + kg), s1 = *(const f32x4*)(scv + kg + 4);
        f32x4 h0 = *(const f32x4*)(shv + kg), h1 = *(const f32x4*)(shv + kg + 4);
#pragma unroll
        for (int j = 0; j < 4; ++j) {
          float v = fmaf(a0[j], s0[j], h0[j]);
          vf[j] = v >= 0.f ? v : alpha * v;
          float v2 = fmaf(a1[j], s1[j], h1[j]);
          vf[4 + j] = v2 >= 0.f ? v2 : alpha * v2;
        }
      }
      bf16x8 ob = __builtin_convertvector(vf, bf16x8);
      *(u16x8*)&As[id * 8] = __builtin_bit_cast(u16x8, ob);
    }
    __syncthreads();

#pragma unroll
    for (int ks = 0; ks < 2; ++ks) {
      bf16x8 af[TM], bfr[TN];
#pragma unroll
      for (int i = 0; i < TM; ++i) {
        const int msub = wrow * TM + i;
        af[i] = __builtin_bit_cast(
            bf16x8, *(const u32x4*)&As[(ks * MS + msub) * 512 + lane * 8]);
      }
#pragma unroll
      for (int j = 0; j < TN; ++j) {
        const int nsub = wcol * TN + j;
        bfr[j] = __builtin_bit_cast(
            bf16x8, *(const u32x4*)&Bs[(ks * NS + nsub) * 512 + lane * 8]);
      }
#pragma unroll
      for (int i = 0; i < TM; ++i)
#pragma unroll
        for (int j = 0; j < TN; ++j)
          acc[i][j] = __builtin_amdgcn_mfma_f32_16x16x32_bf16(af[i], bfr[j],
                                                              acc[i][j], 0, 0, 0);
    }
    __syncthreads();
  }

  const int q = lane >> 4, nn = lane & 15;
#pragma unroll
  for (int i = 0; i < TM; ++i) {
    const int rowb = m0 + wrow * WTM + i * 16 + q * 4;
#pragma unroll
    for (int j = 0; j < TN; ++j) {
      const int col = n0 + wcol * WTN + j * 16 + nn;
      const float bv = biasv ? biasv[col] : 0.f;
#pragma unroll
      for (int r = 0; r < 4; ++r)
        Cp[(long)(rowb + r) * N + col] = acc[i][j][r] + bv;
    }
  }
}

// ---------------------------------------------------------------------------
// Old expert GEMM (f16 dtype; tmp+wn-fold structure) — enc0 and dec1 only.
// ---------------------------------------------------------------------------
template <int BN_, int KE_, int EPB, int NTILE, int KHALVES>
__global__ __launch_bounds__(256, 2) void egemm_k(
    const unsigned short* __restrict__ zpk, const float* __restrict__ wnT,
    const float* __restrict__ bias, const unsigned short* __restrict__ PB,
    float* __restrict__ Cbase, long partStride, int N, int nsubsTot) {
  constexpr int KT2F = KE_ / 32;
  constexpr int KT2 = KT2F / KHALVES;
  constexpr int LK = (KT2 == 8) ? 3 : (KT2 == 4) ? 2 : 1;
  constexpr int NS = BN_ / 16;
  constexpr int TN = NS / 4;
  constexpr int TM = 4;
  constexpr int S = NEXP / EPB;
  constexpr int NC = NTILE * S * KHALVES;
  constexpr int T = EPB * KT2;
  constexpr int U = ((KT2 & 3) == 0) ? 1 : (4 / KT2);

  __shared__ __align__(16) unsigned short As[KT2 * 4 * 512];

  const int tid = threadIdx.x, lane = tid & 63, wid = tid >> 6;
  const int bx = blockIdx.x;
  const int combo = bx % NC;
  const int mb = bx / NC;
  const int ntile = combo % NTILE;
  const int rest = combo / NTILE;
  const int slice = rest % S;
  const int khalf = rest / S;
  const int e0 = slice * EPB;
  const int n0 = ntile * BN_;
  float* __restrict__ Cp = Cbase + (long)(khalf * S + slice) * partStride;
  const int nn = lane & 15, q = lane >> 4;
  const bool addBias = (KHALVES == 1) || (khalf == 0);

  {
    const unsigned short* zb =
        zpk + (long)mb * (KT2F * 4 * 512) + (long)khalf * (KT2 * 4 * 512);
    for (int f = wid; f < KT2 * 4; f += 4)
      async_copy16(zb + f * 512 + lane * 8, &As[f * 512 + lane * 8]);
  }

  const long kstr = (long)nsubsTot * 512;
  const unsigned short* Bq = PB + ((long)e0 * KT2F + khalf * KT2) * kstr +
                             ((long)ntile * NS + wid * TN) * 512 + lane * 8;
  auto baddr = [&](int u) {
    const int ei = u >> LK, kt = u & (KT2 - 1);
    return Bq + ((long)ei * KT2F + kt) * kstr;
  };

  u32x4 ring[4][TN];
#pragma unroll
  for (int t = 0; t < 4; ++t) {
    const unsigned short* a = baddr(t < T ? t : T - 1);
#pragma unroll
    for (int j = 0; j < TN; ++j) ring[t][j] = *(const u32x4*)(a + j * 512);
  }

  __syncthreads();

  f32x4 mainAcc[TM][TN] = {};

  for (int eb = 0; eb < EPB; eb += U) {
#pragma unroll
    for (int uu = 0; uu < U; ++uu) {
      const int ei = eb + uu;
      const int e = e0 + ei;
      f32x4 tmp[TM][TN];
#pragma unroll
      for (int j = 0; j < TN; ++j) {
        const float bv =
            addBias ? bias[(long)e * N + n0 + wid * (TN * 16) + j * 16 + nn]
                    : 0.f;
        f32x4 t4 = {bv, bv, bv, bv};
#pragma unroll
        for (int i = 0; i < TM; ++i) tmp[i][j] = t4;
      }
#pragma unroll
      for (int kt = 0; kt < KT2; ++kt) {
        const int slot = (uu * KT2 + kt) & 3;
#pragma unroll
        for (int i = 0; i < TM; ++i) {
          f16x8 af = __builtin_bit_cast(
              f16x8, *(const u32x4*)&As[(kt * 4 + i) * 512 + lane * 8]);
#pragma unroll
          for (int j = 0; j < TN; ++j)
            tmp[i][j] = __builtin_amdgcn_mfma_f32_16x16x32_f16(
                af, __builtin_bit_cast(f16x8, ring[slot][j]), tmp[i][j], 0, 0,
                0);
        }
        {
          const int u = ei * KT2 + kt;
          const int un = (u + 4 < T) ? (u + 4) : (T - 1);
          const unsigned short* a = baddr(un);
#pragma unroll
          for (int j = 0; j < TN; ++j)
            ring[slot][j] = *(const u32x4*)(a + j * 512);
        }
      }
#pragma unroll
      for (int i = 0; i < TM; ++i) {
        const int rowb = mb * 64 + i * 16 + q * 4;
        f32x4 wn4 = *(const f32x4*)(wnT + (long)e * BATCH + rowb);
#pragma unroll
        for (int j = 0; j < TN; ++j) mainAcc[i][j] += wn4 * tmp[i][j];
      }
    }
  }

#pragma unroll
  for (int i = 0; i < TM; ++i) {
    const int rowb = mb * 64 + i * 16 + q * 4;
#pragma unroll
    for (int j = 0; j < TN; ++j) {
      const int col = n0 + wid * (TN * 16) + j * 16 + nn;
#pragma unroll
      for (int r = 0; r < 4; ++r)
        Cp[(long)(rowb + r) * N + col] = mainAcc[i][j][r];
    }
  }
}

// ---------------------------------------------------------------------------
// egemm2 (round-13): tmp-free expert GEMM for enc1/dec0 (KE=256, N=256).
//   Per-wave tile TM=8 x TN=4 (block 128x256): operand bytes/MFMA drop to
//   A 256B (LDS) + B 128B (L2) -> BW ceilings ~60%/52% MfmaUtil (was 28%,
//   both LDS and L2 pegged at TM=4/TN=2 — rounds 6-12 plateau).
//   tmp eliminated by scaling the A fragment by wn*2^12 in f16 packed math
//   (4 v_pk_mul_f16 per fragment) and accumulating directly into mainAcc;
//   2^-12 + exact fp32 bias fold in the epilogue. Partials stored bf16.
//   Grid 256 = 32 mb x 8 slices (slice in low bits -> XCD-pinned).
// ---------------------------------------------------------------------------
template <int EPB>
__global__ __launch_bounds__(256, 1) void egemm2_k(
    const unsigned short* __restrict__ zpk, const float* __restrict__ wnT,
    const float* __restrict__ bias, const unsigned short* __restrict__ PB,
    unsigned short* __restrict__ Pb, long partStrideH) {
  constexpr int TM = 8, TN = 4;
  constexpr int S = NEXP / EPB;  // 8
  constexpr int T = EPB * 8;     // 64 kt total

  __shared__ __align__(16) unsigned short As[8 * 8 * 512];  // 64 KB

  const int tid = threadIdx.x, lane = tid & 63, wid = tid >> 6;
  const int bx = blockIdx.x;
  const int slice = bx % S;  // low bits -> XCD
  const int mb = bx / S;
  const int e0 = slice * EPB;
  const int nn = lane & 15, q = lane >> 4;

  // Stage A: 64 fragments (kt 0..7, msub 0..7) from two mb64 zpk tiles.
  for (int f = wid; f < 64; f += 4) {
    const int kt = f >> 3, msub = f & 7;
    const unsigned short* src =
        zpk + ((long)(2 * mb + (msub >> 2)) * 32 + kt * 4 + (msub & 3)) * 512;
    async_copy16(src + lane * 8, &As[f * 512 + lane * 8]);
  }

  const long kstr = 16L * 512;
  const unsigned short* Bq =
      PB + (long)e0 * 8 * kstr + ((long)wid * TN) * 512 + lane * 8;

  u32x4 ring[4][TN];
#pragma unroll
  for (int t = 0; t < 4; ++t)
#pragma unroll
    for (int j = 0; j < TN; ++j)
      ring[t][j] = *(const u32x4*)(Bq + (long)t * kstr + j * 512);

  __syncthreads();

  f32x4 acc[TM][TN] = {};

  for (int ei = 0; ei < EPB; ++ei) {
    const int e = e0 + ei;
    // wn' = wn * 2^12 as packed f16 broadcast, per m-subtile (hoisted).
    f16x8 wnh[TM];
#pragma unroll
    for (int i = 0; i < TM; ++i) {
      const float w =
          wnT[(long)e * BATCH + mb * 128 + i * 16 + (lane & 15)] * 4096.f;
      const _Float16 h = (_Float16)w;
      f16x8 v = {h, h, h, h, h, h, h, h};
      wnh[i] = v;
    }
#pragma unroll
    for (int kt = 0; kt < 8; ++kt) {
      const int slot = kt & 3;
#pragma unroll
      for (int i = 0; i < TM; ++i) {
        f16x8 af = __builtin_bit_cast(
            f16x8, *(const u32x4*)&As[(kt * 8 + i) * 512 + lane * 8]);
        f16x8 afs = af * wnh[i];  // v_pk_mul_f16 x4
#pragma unroll
        for (int j = 0; j < TN; ++j)
          acc[i][j] = __builtin_amdgcn_mfma_f32_16x16x32_f16(
              afs, __builtin_bit_cast(f16x8, ring[slot][j]), acc[i][j], 0, 0,
              0);
      }
      {
        const int u = ei * 8 + kt;
        const int un = (u + 4 < T) ? (u + 4) : (T - 1);
#pragma unroll
        for (int j = 0; j < TN; ++j)
          ring[slot][j] = *(const u32x4*)(Bq + (long)un * kstr + j * 512);
      }
    }
  }

  // Epilogue: undo 2^12, add exact fp32 bias combine, store bf16 partial.
#pragma unroll
  for (int i = 0; i < TM; ++i)
#pragma unroll
    for (int j = 0; j < TN; ++j) acc[i][j] *= (1.f / 4096.f);
  for (int ei = 0; ei < EPB; ++ei) {
    const int e = e0 + ei;
    float bs[TN];
#pragma unroll
    for (int j = 0; j < TN; ++j)
      bs[j] = bias[(long)e * 256 + wid * 64 + j * 16 + nn];
#pragma unroll
    for (int i = 0; i < TM; ++i) {
      f32x4 wn4 =
          *(const f32x4*)(wnT + (long)e * BATCH + mb * 128 + i * 16 + q * 4);
#pragma unroll
      for (int j = 0; j < TN; ++j) acc[i][j] += wn4 * bs[j];
    }
  }
  unsigned short* Cp = Pb + (long)slice * partStrideH;
#pragma unroll
  for (int i = 0; i < TM; ++i) {
    const int rowb = mb * 128 + i * 16 + q * 4;
#pragma unroll
    for (int j = 0; j < TN; ++j) {
      const int col = wid * 64 + j * 16 + nn;
#pragma unroll
      for (int r = 0; r < 4; ++r)
        Cp[(long)(rowb + r) * 256 + col] = f2bf(acc[i][j][r]);
    }
  }
}

// ---------------------------------------------------------------------------
// hstats fp32 (enc0): NPARTS compile-time, per-block partials to BS (no
// atomics), H written in place over partial 0.
// ---------------------------------------------------------------------------
template <int NPARTS>
__global__ void hstats_k(float* __restrict__ P, long partStride,
                         f32x4* __restrict__ BS1, f32x4* __restrict__ BS2) {
  const int c0 = (threadIdx.x & 63) * 4;
  const int rg = threadIdx.x >> 6;
  const int rb = blockIdx.x * 8;
  f32x4 s = {0.f, 0.f, 0.f, 0.f}, s2 = {0.f, 0.f, 0.f, 0.f};
#pragma unroll
  for (int it = 0; it < 2; ++it) {
    const long r = rb + it * 4 + rg;
    f32x4 v[NPARTS];
#pragma unroll
    for (int p = 0; p < NPARTS; ++p)
      v[p] = *(const f32x4*)(P + p * partStride + r * 256 + c0);
    f32x4 x = v[0];
#pragma unroll
    for (int p = 1; p < NPARTS; ++p) x += v[p];
    *(f32x4*)(P + r * 256 + c0) = x;
    s += x;
    s2 += x * x;
  }
  __shared__ f32x4 sb[256], qb[256];
  sb[threadIdx.x] = s;
  qb[threadIdx.x] = s2;
  __syncthreads();
  if (threadIdx.x < 64) {
    f32x4 ts = sb[threadIdx.x] + sb[64 + threadIdx.x] + sb[128 + threadIdx.x] +
               sb[192 + threadIdx.x];
    f32x4 tq = qb[threadIdx.x] + qb[64 + threadIdx.x] + qb[128 + threadIdx.x] +
               qb[192 + threadIdx.x];
    BS1[threadIdx.x * 512 + blockIdx.x] = ts;
    BS2[threadIdx.x * 512 + blockIdx.x] = tq;
  }
}

// hstats bf16 (enc1/dec0): 8 bf16 partials -> fp32 H buffer + BS partials.
__global__ void hstats16_k(const unsigned short* __restrict__ P,
                           long partStrideH, float* __restrict__ H,
                           f32x4* __restrict__ BS1, f32x4* __restrict__ BS2) {
  const int c0 = (threadIdx.x & 63) * 4;
  const int rg = threadIdx.x >> 6;
  const int rb = blockIdx.x * 8;
  f32x4 s = {0.f, 0.f, 0.f, 0.f}, s2 = {0.f, 0.f, 0.f, 0.f};
#pragma unroll
  for (int it = 0; it < 2; ++it) {
    const long r = rb + it * 4 + rg;
    u16x4 v[8];
#pragma unroll
    for (int p = 0; p < 8; ++p)
      v[p] = *(const u16x4*)(P + p * partStrideH + r * 256 + c0);
    f32x4 x = {0.f, 0.f, 0.f, 0.f};
#pragma unroll
    for (int p = 0; p < 8; ++p)
#pragma unroll
      for (int j = 0; j < 4; ++j) x[j] += bf2f(v[p][j]);
    *(f32x4*)(H + r * 256 + c0) = x;
    s += x;
    s2 += x * x;
  }
  __shared__ f32x4 sb[256], qb[256];
  sb[threadIdx.x] = s;
  qb[threadIdx.x] = s2;
  __syncthreads();
  if (threadIdx.x < 64) {
    f32x4 ts = sb[threadIdx.x] + sb[64 + threadIdx.x] + sb[128 + threadIdx.x] +
               sb[192 + threadIdx.x];
    f32x4 tq = qb[threadIdx.x] + qb[64 + threadIdx.x] + qb[128 + threadIdx.x] +
               qb[192 + threadIdx.x];
    BS1[threadIdx.x * 512 + blockIdx.x] = ts;
    BS2[threadIdx.x * 512 + blockIdx.x] = tq;
  }
}

// Reduce 512 block-partials per column-group -> finalized scv/shv.
__global__ void sfin_k(const f32x4* __restrict__ BS1,
                       const f32x4* __restrict__ BS2,
                       const float* __restrict__ g, const float* __restrict__ b,
                       float* __restrict__ scv, float* __restrict__ shv) {
  const int cg = blockIdx.x;
  f32x4 s1 = BS1[cg * 512 + threadIdx.x] + BS1[cg * 512 + 256 + threadIdx.x];
  f32x4 s2 = BS2[cg * 512 + threadIdx.x] + BS2[cg * 512 + 256 + threadIdx.x];
  __shared__ f32x4 sb[256], qb[256];
  sb[threadIdx.x] = s1;
  qb[threadIdx.x] = s2;
  __syncthreads();
  for (int st = 128; st > 0; st >>= 1) {
    if (threadIdx.x < st) {
      sb[threadIdx.x] += sb[threadIdx.x + st];
      qb[threadIdx.x] += qb[threadIdx.x + st];
    }
    __syncthreads();
  }
  if (threadIdx.x < 4) {
    const int c = cg * 4 + threadIdx.x;
    float mu = sb[0][threadIdx.x] * (1.f / BATCH);
    float var = qb[0][threadIdx.x] * (1.f / BATCH) - mu * mu;
    float isig = 1.f / sqrtf(var + 1e-5f);
    float sc_ = g[c] * isig;
    scv[c] = sc_;
    shv[c] = b[c] - mu * sc_;
  }
}

// BN stats (MNet path).
__global__ void stats_k(const float* __restrict__ H, int C,
                        const float* __restrict__ g, const float* __restrict__ b,
                        float* __restrict__ scv, float* __restrict__ shv) {
  const int c0 = blockIdx.x * 4;
  f32x4 s = {0.f, 0.f, 0.f, 0.f}, s2 = {0.f, 0.f, 0.f, 0.f};
  for (int r = threadIdx.x; r < BATCH; r += 256) {
    f32x4 x = *(const f32x4*)(H + (long)r * C + c0);
    s += x;
    s2 += x * x;
  }
  __shared__ f32x4 sb[256], qb[256];
  sb[threadIdx.x] = s;
  qb[threadIdx.x] = s2;
  __syncthreads();
  for (int st = 128; st > 0; st >>= 1) {
    if (threadIdx.x < st) {
      sb[threadIdx.x] += sb[threadIdx.x + st];
      qb[threadIdx.x] += qb[threadIdx.x + st];
    }
    __syncthreads();
  }
  if (threadIdx.x < 4) {
    const int c = c0 + threadIdx.x;
    float mu = sb[0][threadIdx.x] * (1.f / BATCH);
    float var = qb[0][threadIdx.x] * (1.f / BATCH) - mu * mu;
    float isig = 1.f / sqrtf(var + 1e-5f);
    float sc_ = g[c] * isig;
    scv[c] = sc_;
    shv[c] = b[c] - mu * sc_;
  }
}

// zpk = packed-A-fragment f16 of prelu(sc*H+sh); C=256 fixed.
__global__ void zbuild_pk(const float* __restrict__ H,
                          const float* __restrict__ scv,
                          const float* __restrict__ shv,
                          const float* __restrict__ alphaPtr,
                          unsigned short* __restrict__ zpk) {
  const int c = blockIdx.x * 256 + threadIdx.x;  // 131072 total
  const float alpha = alphaPtr[0];
  const int mb = c >> 11, r = c & 2047;
  const int kt = r >> 8, q2 = r & 255;
  const int msub = q2 >> 6, ln = q2 & 63;
  const int row = mb * 64 + msub * 16 + (ln & 15);
  const int col = kt * 32 + (ln >> 4) * 8;
  const float* src = H + (long)row * 256 + col;
  f32x4 a0 = *(const f32x4*)src, a1 = *(const f32x4*)(src + 4);
  f32x4 s0 = *(const f32x4*)(scv + col), s1 = *(const f32x4*)(scv + col + 4);
  f32x4 h0 = *(const f32x4*)(shv + col), h1 = *(const f32x4*)(shv + col + 4);
  u16x8 o;
#pragma unroll
  for (int j = 0; j < 4; ++j) {
    float v = fmaf(a0[j], s0[j], h0[j]);
    v = v >= 0.f ? v : alpha * v;
    o[j] = f2h(v);
    float v2 = fmaf(a1[j], s1[j], h1[j]);
    v2 = v2 >= 0.f ? v2 : alpha * v2;
    o[4 + j] = f2h(v2);
  }
  *(u16x8*)(zpk + (long)c * 8) = o;
}

// w = prelu(bn(H3)) fp32; per-block sums to wps (no atomic).
__global__ void wbuild_k(const float* __restrict__ G, const float* __restrict__ scv,
                         const float* __restrict__ shv,
                         const float* __restrict__ alphaPtr,
                         float* __restrict__ w, float* __restrict__ wps) {
  const int idx = blockIdx.x * 256 + threadIdx.x;  // 65536 threads
  const float alpha = alphaPtr[0];
  const int c0 = (idx * 4) & 63;
  f32x4 x = *(const f32x4*)(G + (long)idx * 4);
  f32x4 sv = *(const f32x4*)(scv + c0);
  f32x4 hv = *(const f32x4*)(shv + c0);
  f32x4 o;
  float part = 0.f;
#pragma unroll
  for (int j = 0; j < 4; ++j) {
    float v = fmaf(x[j], sv[j], hv[j]);
    v = v >= 0.f ? v : alpha * v;
    o[j] = v;
    part += v;
  }
  *(f32x4*)(w + (long)idx * 4) = o;
  __shared__ float sb[256];
  sb[threadIdx.x] = part;
  __syncthreads();
  for (int st = 128; st > 0; st >>= 1) {
    if (threadIdx.x < st) sb[threadIdx.x] += sb[threadIdx.x + st];
    __syncthreads();
  }
  if (threadIdx.x == 0) wps[blockIdx.x] = sb[0];
}

// Fused: wnT (blocks 0..1023; reduces wps in-block); x0 -> packed f16
// (blocks 1024..1151).
__global__ void wnTcast_k(const float* __restrict__ w,
                          const float* __restrict__ wps,
                          float* __restrict__ wnT, const float* __restrict__ x0,
                          unsigned short* __restrict__ x0pk) {
  const int bx = blockIdx.x;
  if (bx < 1024) {
    __shared__ float sb[256];
    sb[threadIdx.x] = wps[threadIdx.x];
    __syncthreads();
    for (int st = 128; st > 0; st >>= 1) {
      if (threadIdx.x < st) sb[threadIdx.x] += sb[threadIdx.x + st];
      __syncthreads();
    }
    const float inv = 1.0f / sb[0];
    const int idx = bx * 256 + threadIdx.x;
    const int e = idx >> 12, b2 = idx & 4095;
    wnT[idx] = w[(long)b2 * NEXP + e] * inv;
  } else {
    const int c = (bx - 1024) * 256 + threadIdx.x;  // 32768
    const int mb = c >> 9, r = c & 511;
    const int kt = r >> 8, q2 = r & 255;
    const int msub = q2 >> 6, ln = q2 & 63;
    const int row = mb * 64 + msub * 16 + (ln & 15);
    const int col = kt * 32 + (ln >> 4) * 8;
    const float* src = x0 + (long)row * 64 + col;
    f32x4 a0 = *(const f32x4*)src, a1 = *(const f32x4*)(src + 4);
    u16x8 o;
#pragma unroll
    for (int j = 0; j < 4; ++j) {
      o[j] = f2h(a0[j]);
      o[4 + j] = f2h(a1[j]);
    }
    *(u16x8*)(x0pk + (long)c * 8) = o;
  }
}

// MNet weights -> fragment-major bf16 (9216 chunks).
__global__ void mnetprep_k(const float* __restrict__ w0,
                           const float* __restrict__ w1,
                           const float* __restrict__ w2,
                           unsigned short* __restrict__ PB) {
  const int t = blockIdx.x * 256 + threadIdx.x;
  const float* W;
  int nsubs, shI;
  long loc;
  if (t < 4096) { W = w0; nsubs = 16; shI = 7; loc = t; }            // mW1
  else if (t < 8192) { W = w1; nsubs = 8; shI = 8; loc = t - 4096; } // mW2
  else if (t < 9216) { W = w2; nsubs = 4; shI = 7; loc = t - 8192; } // mW3
  else return;
  const int lane = (int)(loc & 63);
  const long frag = loc >> 6;
  const int nsub = (int)(frag % nsubs);
  const long ktile = frag / nsubs;
  const int n = nsub * 16 + (lane & 15);
  const int k = (int)(ktile * 32 + (lane >> 4) * 8);
  const int e = k >> shI;
  const int i0 = k & ((1 << shI) - 1);
  const int O = nsubs * 16;
  const float* src = W + ((long)e * O + n) * (1 << shI) + i0;
  f32x4 a0 = *(const f32x4*)src, a1 = *(const f32x4*)(src + 4);
  u16x8 o;
#pragma unroll
  for (int j = 0; j < 4; ++j) {
    o[j] = f2bf(a0[j]);
    o[4 + j] = f2bf(a1[j]);
  }
  *(u16x8*)(PB + (long)t * 8) = o;
}

// Expert weights -> fragment-major f16, one layer per dispatch.
__global__ void eprep_k(const float* __restrict__ W,
                        unsigned short* __restrict__ PB, int nsubs, int shI,
                        long totalChunks) {
  const long t = (long)blockIdx.x * 256 + threadIdx.x;
  if (t >= totalChunks) return;
  const int lane = (int)(t & 63);
  const long frag = t >> 6;
  const int nsub = (int)(frag % nsubs);
  const long ktile = frag / nsubs;
  const int n = nsub * 16 + (lane & 15);
  const int k = (int)(ktile * 32 + (lane >> 4) * 8);
  const int e = k >> shI;
  const int i0 = k & ((1 << shI) - 1);
  const int O = nsubs * 16;
  const float* src = W + ((long)e * O + n) * (1 << shI) + i0;
  f32x4 a0 = *(const f32x4*)src, a1 = *(const f32x4*)(src + 4);
  u16x8 o;
#pragma unroll
  for (int j = 0; j < 4; ++j) {
    o[j] = f2h(a0[j]);
    o[4 + j] = f2h(a1[j]);
  }
  *(u16x8*)(PB + (long)t * 8) = o;
}

// Final reduce, compile-time NP (unrolled independent loads).
template <int NP>
__global__ void reduceN_k(const float* __restrict__ P, long partStride,
                          float* __restrict__ out, int total4) {
  const int idx = blockIdx.x * 256 + threadIdx.x;
  if (idx >= total4) return;
  f32x4 v[NP];
#pragma unroll
  for (int p = 0; p < NP; ++p)
    v[p] = *(const f32x4*)(P + p * partStride + (long)idx * 4);
  f32x4 s = v[0];
#pragma unroll
  for (int p = 1; p < NP; ++p) s += v[p];
  *(f32x4*)(out + (long)idx * 4) = s;
}

// ---------------------------------------------------------------------------
extern "C" void kernel_launch(void* const* d_in, const int* in_sizes, int n_in,
                              void* d_out, int out_size, void* d_ws, size_t ws_size,
                              hipStream_t stream) {
  const float* m0 = (const float*)d_in[0];
  const float* x0 = (const float*)d_in[1];
  const float* mW1 = (const float*)d_in[2];
  const float* mb1 = (const float*)d_in[3];
  const float* mg1 = (const float*)d_in[4];
  const float* mbe1 = (const float*)d_in[5];
  const float* ma1 = (const float*)d_in[6];
  const float* mW2 = (const float*)d_in[7];
  const float* mb2 = (const float*)d_in[8];
  const float* mg2 = (const float*)d_in[9];
  const float* mbe2 = (const float*)d_in[10];
  const float* ma2 = (const float*)d_in[11];
  const float* mW3 = (const float*)d_in[12];
  const float* mb3 = (const float*)d_in[13];
  const float* mg3 = (const float*)d_in[14];
  const float* mbe3 = (const float*)d_in[15];
  const float* ma3 = (const float*)d_in[16];
  const float* Wenc0 = (const float*)d_in[17];
  const float* benc0 = (const float*)d_in[18];
  const float* Wenc1 = (const float*)d_in[19];
  const float* benc1 = (const float*)d_in[20];
  const float* Wdec0 = (const float*)d_in[21];
  const float* bdec0 = (const float*)d_in[22];
  const float* Wdec1 = (const float*)d_in[23];
  const float* bdec1 = (const float*)d_in[24];
  const float* bng = (const float*)d_in[25];
  const float* bnb = (const float*)d_in[26];
  const float* aexp = (const float*)d_in[27];

  const long PSP32 = (long)BATCH * 256 + 64;   // fp32 partial stride (enc0)
  const long PSPH = (long)BATCH * 256 + 128;   // bf16 partial stride (u16)
  const long PSD = (long)BATCH * 64 + 64;      // dec1 fp32 partial stride

  char* base = (char*)d_ws;
  size_t off = 0;
  auto alloc = [&](size_t bytes) {
    void* p = base + off;
    off = (off + bytes + 255) & ~(size_t)255;
    return p;
  };
  unsigned short* PBm = (unsigned short*)alloc(9216L * 16);    // MNet bf16
  unsigned short* PBe = (unsigned short*)alloc(524288L * 16);  // 8.39 MB/layer
  // Pb region: max(4*PSP32*4, 8*PSPH*2, 16*PSD*4) bytes
  size_t pbBytes = 16UL * PSD * 4;
  if (8UL * PSPH * 2 > pbBytes) pbBytes = 8UL * PSPH * 2;
  if (4UL * PSP32 * 4 > pbBytes) pbBytes = 4UL * PSP32 * 4;
  void* PbBase = alloc(pbBytes);  // ~16.8 MB
  float* Pb32 = (float*)PbBase;
  unsigned short* Pb16 = (unsigned short*)PbBase;
  float* P0 = Pb32;
  float* P1 = Pb32 + (long)BATCH * 256;
  float* Hbuf = (float*)alloc((size_t)BATCH * 256 * 4);  // 4 MB
  unsigned short* zApk = (unsigned short*)alloc(BATCH * 256 * 2);
  unsigned short* zBpk = (unsigned short*)alloc(BATCH * 256 * 2);
  unsigned short* x0pk = (unsigned short*)alloc(BATCH * 64 * 2);
  float* wbuf = (float*)alloc(BATCH * 64 * 4);
  float* wnT = (float*)alloc((size_t)NEXP * BATCH * 4);
  f32x4* BS1 = (f32x4*)alloc(64 * 512 * 16);
  f32x4* BS2 = (f32x4*)alloc(64 * 512 * 16);
  float* scv = (float*)alloc(256 * 4);
  float* shv = (float*)alloc(256 * 4);
  float* wps = (float*)alloc(256 * 4);

  const dim3 blk(256);

  mnetprep_k<<<36, blk, 0, stream>>>(mW1, mW2, mW3, PBm);

  // ---- MNet (bf16)
  gemm_k<64, 128, 2, 2, AM_PLAIN><<<dim3(64, 2, 1), blk, 0, stream>>>(
      m0, nullptr, nullptr, nullptr, PBm, 128, 16, P0, mb1, 256, 2);
  stats_k<<<64, blk, 0, stream>>>(P0, 256, mg1, mbe1, scv, shv);
  gemm_k<64, 128, 2, 2, AM_BN><<<dim3(64, 1, 1), blk, 0, stream>>>(
      P0, scv, shv, ma1, PBm + 4096L * 8, 256, 8, P1, mb2, 128, 4);
  stats_k<<<32, blk, 0, stream>>>(P1, 128, mg2, mbe2, scv, shv);
  gemm_k<64, 64, 2, 2, AM_BN><<<dim3(64, 1, 1), blk, 0, stream>>>(
      P1, scv, shv, ma2, PBm + 8192L * 8, 128, 4, P0, mb3, 64, 2);
  stats_k<<<16, blk, 0, stream>>>(P0, 64, mg3, mbe3, scv, shv);
  wbuild_k<<<256, blk, 0, stream>>>(P0, scv, shv, ma3, wbuf, wps);
  wnTcast_k<<<1152, blk, 0, stream>>>(wbuf, wps, wnT, x0, x0pk);

  // ---- enc0 (old egemm, f16): KE=64, 4 fp32 partials
  eprep_k<<<512, blk, 0, stream>>>(Wenc0, PBe, 16, 6, 131072);
  egemm_k<128, 64, 16, 2, 1><<<dim3(512), blk, 0, stream>>>(
      x0pk, wnT, benc0, PBe, Pb32, PSP32, 256, 16);
  hstats_k<4><<<512, blk, 0, stream>>>(Pb32, PSP32, BS1, BS2);
  sfin_k<<<64, blk, 0, stream>>>(BS1, BS2, bng, bnb, scv, shv);
  zbuild_pk<<<512, blk, 0, stream>>>(Pb32, scv, shv, aexp, zApk);

  // ---- enc1 (egemm2): 8 bf16 partials
  eprep_k<<<2048, blk, 0, stream>>>(Wenc1, PBe, 16, 8, 524288);
  egemm2_k<8><<<dim3(256), blk, 0, stream>>>(zApk, wnT, benc1, PBe, Pb16, PSPH);
  hstats16_k<<<512, blk, 0, stream>>>(Pb16, PSPH, Hbuf, BS1, BS2);
  sfin_k<<<64, blk, 0, stream>>>(BS1, BS2, bng, bnb, scv, shv);
  zbuild_pk<<<512, blk, 0, stream>>>(Hbuf, scv, shv, aexp, zBpk);

  // ---- dec0 (egemm2)
  eprep_k<<<2048, blk, 0, stream>>>(Wdec0, PBe, 16, 8, 524288);
  egemm2_k<8><<<dim3(256), blk, 0, stream>>>(zBpk, wnT, bdec0, PBe, Pb16, PSPH);
  hstats16_k<<<512, blk, 0, stream>>>(Pb16, PSPH, Hbuf, BS1, BS2);
  sfin_k<<<64, blk, 0, stream>>>(BS1, BS2, bng, bnb, scv, shv);
  zbuild_pk<<<512, blk, 0, stream>>>(Hbuf, scv, shv, aexp, zApk);

  // ---- dec1 (old egemm, f16): 16 fp32 partials
  eprep_k<<<512, blk, 0, stream>>>(Wdec1, PBe, 4, 8, 131072);
  egemm_k<64, 256, 8, 1, 2><<<dim3(1024), blk, 0, stream>>>(
      zApk, wnT, bdec1, PBe, Pb32, PSD, 64, 4);
  reduceN_k<16><<<256, blk, 0, stream>>>(Pb32, PSD, (float*)d_out, 65536);

  (void)in_sizes; (void)n_in; (void)out_size; (void)ws_size;
}